// Round 9
// baseline (291.367 us; speedup 1.0000x reference)
//
#include <hip/hip_runtime.h>
#include <hip/hip_bf16.h>

#define Bn 8
#define Qn 300
#define Pn 5
#define RSn 256
#define QSn 768
#define NCn 396
#define MTOT 10880
#define THRL -1.3862943611198906f   // log(0.2/0.8): sigmoid(x)>0.2 <=> x>THRL

typedef __attribute__((ext_vector_type(8))) short short8;
typedef __attribute__((ext_vector_type(4))) float float4v;

__device__ inline float wred(float v){
  #pragma unroll
  for (int off = 32; off; off >>= 1) v += __shfl_xor(v, off);
  return v;
}

__device__ __forceinline__ unsigned short f2bf(float f){
  union { float f; unsigned int u; } c; c.f = f;
  return (unsigned short)((c.u + 0x7FFF + ((c.u >> 16) & 1)) >> 16);   // RNE
}

// =====================================================================
// D1: k_front — [0,768): convW f32 -> bf16 swizzled Wswz[s][kc][lk][n][8]
//               768: mask detect ; [769,809): query pooling (12-chain ILP);
//               [809,821): zero ctxsum+hpre ; [821,825): zero out
// =====================================================================
__global__ __launch_bounds__(256, 4) void k_front(
    const float* cw0, const float* cw1, const float* cw2, const float* cw3,
    short* Wswz, const int* __restrict__ mk0, int* det,
    const float* __restrict__ pl, const float* __restrict__ hs,
    float* pooled, int* flags, float* ctxsum, float* outz){
  int bx = blockIdx.x;
  int t = threadIdx.x;
  if (bx < 768){
    int s = bx / 192;
    int linear = (bx % 192)*256 + t;
    int q = linear & 63, n = linear >> 6;
    const float* src = (s==0)?cw0:(s==1)?cw1:(s==2)?cw2:cw3;
    float4 f = *(const float4*)(src + (size_t)n*256 + q*4);
    int kc = q >> 3, lk = (q >> 1) & 3, e0 = (q & 1)*4;
    short* dst = Wswz + ((size_t)(s*8 + kc))*24576 + lk*6144 + n*8 + e0;
    short4 sv;
    sv.x = (short)f2bf(f.x); sv.y = (short)f2bf(f.y);
    sv.z = (short)f2bf(f.z); sv.w = (short)f2bf(f.w);
    *(short4*)dst = sv;
    return;
  }
  if (bx == 768){
    __shared__ int r0[4], r1[4];
    const int* mm = mk0 + t*32;
    int d0 = 0, d1 = 0;
    #pragma unroll 8
    for (int i = 0; i < 32; ++i){
      int v = mm[i];
      d0 |= (v != 0 && v != 1);
      d1 |= (v != 0 && v != 0x3F800000);
    }
    unsigned long long bal0 = __ballot(d0), bal1 = __ballot(d1);
    int wid = t >> 6;
    if ((t & 63) == 0){ r0[wid] = (bal0 != 0ull); r1[wid] = (bal1 != 0ull); }
    __syncthreads();
    if (t == 0){
      det[0] = r0[0] | r0[1] | r0[2] | r0[3];
      det[1] = r1[0] | r1[1] | r1[2] | r1[3];
    }
    return;
  }
  if (bx >= 821){
    int idx = ((bx - 821)*256 + t)*4;
    if (idx < Bn*NCn) *(float4*)(outz + idx) = (float4){0.f,0.f,0.f,0.f};
    return;
  }
  if (bx >= 809){
    int idx = ((bx - 809)*256 + t)*4;      // zero ctxsum(6144)+hpre(6144)
    *(float4*)(ctxsum + idx) = (float4){0.f,0.f,0.f,0.f};
    return;
  }
  // ---- query pooling: 12 independent accumulator chains (300 = 25x12)
  __shared__ float msk[Qn];
  int bb = (bx - 769) / Pn, p = (bx - 769) % Pn;
  for (int q = t; q < Qn; q += 256)
    msk[q] = (pl[(bb*Qn + q)*Pn + p] > THRL) ? 1.f : 0.f;
  __syncthreads();
  const float* hb = hs + (size_t)bb*Qn*RSn + t;
  float sA[12];
  #pragma unroll
  for (int i = 0; i < 12; ++i) sA[i] = 0.f;
  float cnt = 0.f;
  for (int q0 = 0; q0 < Qn; q0 += 12){
    #pragma unroll
    for (int i = 0; i < 12; ++i){
      float m = msk[q0 + i];
      cnt += m;
      sA[i] = fmaf(m, hb[(size_t)(q0 + i)*RSn], sA[i]);
    }
  }
  float ssum = ((sA[0]+sA[1]) + (sA[2]+sA[3])) + ((sA[4]+sA[5]) + (sA[6]+sA[7]))
             + ((sA[8]+sA[9]) + (sA[10]+sA[11]));
  pooled[(bb*Pn + p)*RSn + t] = (cnt > 0.f) ? ssum / cnt : 0.f;
  if (t == 0) flags[bb*Pn + p] = (cnt > 0.f) ? 1 : 0;
}

// =====================================================================
// D2: k_pgemm — 128 threads / 2 waves per block, M=8 tokens.
//   logical blocks [0,1360): fused pool + MFMA GEMM + bias + LN + token-sum
//   blocks [1360,1408): query tokens + LN -> qt
// Round-9: grid-limited occupancy fix — 1360 small UNSYNCED blocks
// (5.3/CU supply) so different blocks overlap different phases on a CU
// (round-8 chain-math: per-block serial chain x 2.66 synced batches was
// the 42us). Pool phase uses verified float4 token-pair loads (round 7).
// XCD swizzle keeps each 128B feat-line's two half-users on one XCD.
// MFMA rows 8..15 are garbage (M=8); masked in the epilogue (lk>=2 -> 0).
// =====================================================================
__global__ __launch_bounds__(128, 2) void k_pgemm(
    const float* fe0, const float* po0, const void* ma0,
    const float* fe1, const float* po1, const void* ma1,
    const float* fe2, const float* po2, const void* ma2,
    const float* fe3, const float* po3, const void* ma3,
    const int* __restrict__ det, const short* __restrict__ Wswz,
    const float* cb0, const float* cb1, const float* cb2, const float* cb3,
    const float* lg0, const float* lb0, const float* lg1, const float* lb1,
    const float* lg2, const float* lb2, const float* lg3, const float* lb3,
    float* __restrict__ ctxsum,
    const float* __restrict__ lq, const float* __restrict__ Wq,
    const float* __restrict__ bq, const float* __restrict__ qng,
    const float* __restrict__ qnb, const float* __restrict__ pooled,
    const int* __restrict__ flags, float* qt){
  __shared__ short As[16*264];        // 8.25 KB A-tile [m][k], pitch 264
  __shared__ float imls[8];
  __shared__ float lsum[2][16], lsq[2][16];
  __shared__ float pq[256];
  __shared__ float s1s[2], s2s[2];
  int pblk = blockIdx.x;
  int t = threadIdx.x;

  if (pblk >= 1360){
    // ---- query tokens + LN (128 threads, 6 cols/thread)
    int qbx = pblk - 1360;
    int b = qbx / 6, j = qbx % 6;
    float v0 = lq[j*QSn + t      ];
    float v1 = lq[j*QSn + t + 128];
    float v2 = lq[j*QSn + t + 256];
    float v3 = lq[j*QSn + t + 384];
    float v4 = lq[j*QSn + t + 512];
    float v5 = lq[j*QSn + t + 640];
    int any = flags[b*Pn] | flags[b*Pn+1] | flags[b*Pn+2] | flags[b*Pn+3] | flags[b*Pn+4];
    if (j > 0 && any){
      pq[t      ] = pooled[(b*Pn + (j-1))*RSn + t      ];
      pq[t + 128] = pooled[(b*Pn + (j-1))*RSn + t + 128];
      __syncthreads();
      float a0=0.f,a1=0.f,a2=0.f,a3=0.f,a4=0.f,a5=0.f;
      #pragma unroll 8
      for (int c = 0; c < RSn; ++c){
        float pv = pq[c];
        const float* wr = Wq + c*QSn + t;
        a0 = fmaf(pv, wr[0],   a0);
        a1 = fmaf(pv, wr[128], a1);
        a2 = fmaf(pv, wr[256], a2);
        a3 = fmaf(pv, wr[384], a3);
        a4 = fmaf(pv, wr[512], a4);
        a5 = fmaf(pv, wr[640], a5);
      }
      v0 += a0 + bq[t];       v1 += a1 + bq[t+128];
      v2 += a2 + bq[t+256];   v3 += a3 + bq[t+384];
      v4 += a4 + bq[t+512];   v5 += a5 + bq[t+640];
    }
    float sm = (v0+v1) + (v2+v3) + (v4+v5);
    float sq = (v0*v0+v1*v1) + (v2*v2+v3*v3) + (v4*v4+v5*v5);
    sm = wred(sm); sq = wred(sq);
    int wid = t >> 6, lane = t & 63;
    if (lane == 0){ s1s[wid] = sm; s2s[wid] = sq; }
    __syncthreads();
    float S  = s1s[0] + s1s[1];
    float SQ = s2s[0] + s2s[1];
    float mu = S * (1.f/QSn), var = SQ * (1.f/QSn) - mu*mu;
    float rs = rsqrtf(var + 1e-5f);
    float* o = qt + (b*6 + j)*QSn;
    o[t      ] = (v0 - mu)*rs*qng[t      ] + qnb[t      ];
    o[t + 128] = (v1 - mu)*rs*qng[t + 128] + qnb[t + 128];
    o[t + 256] = (v2 - mu)*rs*qng[t + 256] + qnb[t + 256];
    o[t + 384] = (v3 - mu)*rs*qng[t + 384] + qnb[t + 384];
    o[t + 512] = (v4 - mu)*rs*qng[t + 512] + qnb[t + 512];
    o[t + 640] = (v5 - mu)*rs*qng[t + 640] + qnb[t + 640];
    return;
  }

  // ---- XCD swizzle: within each 16-physical group, physicals j and j+8
  // (same XCD under p%8 round-robin) handle logical pair (2k, 2k+1) so
  // both 64B halves of each 128B feat/pos line stay in one XCD's L2.
  int q16 = pblk >> 4, jj = pblk & 15;
  int blk = (q16 << 4) + ((jj & 7) << 1) + (jj >> 3);

  int m0 = blk * 8;
  int s, H, OWlog, b0;
  const float *F, *Pp; const void* M;
  const float *CB, *LG, *LB;
  if (m0 < 8192){ s=0; F=fe0; Pp=po0; M=ma0; H=64; OWlog=5; b0=m0>>10;
                  CB=cb0; LG=lg0; LB=lb0; }
  else if (m0 < 10240){ s=1; F=fe1; Pp=po1; M=ma1; H=32; OWlog=4; b0=(m0-8192)>>8;
                  CB=cb1; LG=lg1; LB=lb1; }
  else if (m0 < 10752){ s=2; F=fe2; Pp=po2; M=ma2; H=16; OWlog=3; b0=(m0-10240)>>6;
                  CB=cb2; LG=lg2; LB=lb2; }
  else { s=3; F=fe3; Pp=po3; M=ma3; H=8; OWlog=2; b0=(m0-10752)>>4;
                  CB=cb3; LG=lg3; LB=lb3; }
  int HH = H*H;
  int OWm = (H >> 1) - 1;
  int mode = (det[0] == 0) ? 0 : ((det[1] == 0) ? 2 : 1);

  // ---- token-pair geometry (pair slotp = t&3; tokens mA, mA+1)
  int slotp = t & 3;
  int mA = m0 + slotp*2;
  int ltl;
  if (s == 0)      ltl = mA & 1023;
  else if (s == 1) ltl = mA & 255;
  else if (s == 2) ltl = mA & 63;
  else             ltl = mA & 15;
  int ph = ltl >> OWlog, pw = ltl & OWm;   // pw even
  int i00 = ph*2*H + pw*2;                 // multiple of 4 -> float4 aligned
  int mbase = b0*HH;

  // ---- mask weights for both tokens of the pair (16B-span reads)
  float w0A,w1A,w2A,w3A, w0B,w1B,w2B,w3B;
  if (mode == 0){
    const int* Mi = (const int*)M + mbase + i00;
    int4 ma = *(const int4*)(Mi);
    int4 mb = *(const int4*)(Mi + H);
    w0A = ma.x?0.f:1.f; w1A = ma.y?0.f:1.f; w2A = mb.x?0.f:1.f; w3A = mb.y?0.f:1.f;
    w0B = ma.z?0.f:1.f; w1B = ma.w?0.f:1.f; w2B = mb.z?0.f:1.f; w3B = mb.w?0.f:1.f;
  } else if (mode == 1){
    const unsigned char* Mb = (const unsigned char*)M + mbase + i00;
    uchar4 av = *(const uchar4*)(Mb);
    uchar4 bv = *(const uchar4*)(Mb + H);
    w0A = av.x?0.f:1.f; w1A = av.y?0.f:1.f; w2A = bv.x?0.f:1.f; w3A = bv.y?0.f:1.f;
    w0B = av.z?0.f:1.f; w1B = av.w?0.f:1.f; w2B = bv.z?0.f:1.f; w3B = bv.w?0.f:1.f;
  } else {
    const float* Mf = (const float*)M + mbase + i00;
    float4 ma = *(const float4*)(Mf);
    float4 mb = *(const float4*)(Mf + H);
    w0A = 1.f-ma.x; w1A = 1.f-ma.y; w2A = 1.f-mb.x; w3A = 1.f-mb.y;
    w0B = 1.f-ma.z; w1B = 1.f-ma.w; w2B = 1.f-mb.z; w3B = 1.f-mb.w;
  }
  float msA = w0A+w1A+w2A+w3A, msB = w0B+w1B+w2B+w3B;
  float imA = 1.f / fmaxf(msA*0.25f, 1e-6f);
  float imB = 1.f / fmaxf(msB*0.25f, 1e-6f);
  float scA = 0.25f*imA, scB = 0.25f*imB;
  if (t < 4){ imls[slotp*2] = imA; imls[slotp*2 + 1] = imB; }

  // ---- pool 256 channels into As[m][k]: cg = t>>2 (0..31), float4 pair
  // loads, 8 fully-unrolled independent rounds.
  {
    int cg = t >> 2;
    size_t base = (size_t)(b0*256 + cg)*HH + i00;
    const float* Fp = F + base;
    const float* Pq2 = Pp + base;
    const size_t stride = (size_t)32*HH;
    int rowA = slotp*2*264, rowB = rowA + 264;
    #pragma unroll
    for (int r = 0; r < 8; ++r){
      float4 f0 = *(const float4*)(Fp);
      float4 f1 = *(const float4*)(Fp + H);
      float4 p0 = *(const float4*)(Pq2);
      float4 p1 = *(const float4*)(Pq2 + H);
      float xA = (f0.x+p0.x)*w0A + (f0.y+p0.y)*w1A + (f1.x+p1.x)*w2A + (f1.y+p1.y)*w3A;
      float xB = (f0.z+p0.z)*w0B + (f0.w+p0.w)*w1B + (f1.z+p1.z)*w2B + (f1.w+p1.w)*w3B;
      As[rowA + cg + r*32] = (short)f2bf(xA*scA);
      As[rowB + cg + r*32] = (short)f2bf(xB*scB);
      Fp += stride; Pq2 += stride;
    }
  }
  __syncthreads();

  // ---- A fragments (rows 8..15 are stale LDS garbage; their MFMA rows
  // are independent and masked out in the epilogue)
  int wid = t >> 6, l = t & 63;
  int lm = l & 15, lk = l >> 4;
  int nfb = wid * 24;
  short8 aReg[8];
  #pragma unroll
  for (int kc = 0; kc < 8; ++kc)
    aReg[kc] = *(const short8*)(As + lm*264 + kc*32 + lk*8);

  float4v acc[24];
  #pragma unroll
  for (int nf = 0; nf < 24; ++nf) acc[nf] = (float4v){0.f,0.f,0.f,0.f};

  // ---- K loop: B fragments straight from L2 (pre-swizzled, 16B/lane)
  const short* Bb = Wswz + ((size_t)(s*8))*24576 + lk*6144 + nfb*128 + lm*8;
  #pragma unroll
  for (int kc = 0; kc < 8; ++kc){
    const short* bp = Bb + kc*24576;
    #pragma unroll
    for (int nf = 0; nf < 24; ++nf){
      short8 bf = *(const short8*)(bp + nf*128);
      acc[nf] = __builtin_amdgcn_mfma_f32_16x16x32_bf16(aReg[kc], bf, acc[nf], 0, 0, 0);
    }
  }

  // ---- epilogue: bias, per-row LN (rows 0..7 valid), token-sum -> ctxsum
  float im4[4];
  #pragma unroll
  for (int r = 0; r < 4; ++r) im4[r] = imls[(lk*4 + r) & 7];

  float sum[4] = {0,0,0,0}, sq[4] = {0,0,0,0};
  #pragma unroll
  for (int nf = 0; nf < 24; ++nf){
    float cbv = CB[(nfb+nf)*16 + lm];
    #pragma unroll
    for (int r = 0; r < 4; ++r){
      float p = acc[nf][r] + cbv*im4[r];
      acc[nf][r] = p;
      sum[r] += p;
      sq[r] = fmaf(p, p, sq[r]);
    }
  }
  #pragma unroll
  for (int r = 0; r < 4; ++r){
    #pragma unroll
    for (int off = 1; off < 16; off <<= 1){
      sum[r] += __shfl_xor(sum[r], off);
      sq[r]  += __shfl_xor(sq[r],  off);
    }
  }
  if (lm == 0){
    #pragma unroll
    for (int r = 0; r < 4; ++r){
      lsum[wid][lk*4 + r] = sum[r];
      lsq[wid][lk*4 + r]  = sq[r];
    }
  }
  __syncthreads();
  float mu[4], rs[4];
  #pragma unroll
  for (int r = 0; r < 4; ++r){
    int row = lk*4 + r;
    float S  = lsum[0][row] + lsum[1][row];
    float SQ = lsq[0][row]  + lsq[1][row];
    mu[r] = S * (1.f/768.f);
    float var = SQ * (1.f/768.f) - mu[r]*mu[r];
    rs[r] = rsqrtf(var + 1e-5f);
  }
  #pragma unroll
  for (int nf = 0; nf < 24; ++nf){
    int n = (nfb+nf)*16 + lm;
    float g = LG[n], bv = LB[n];
    float tv = 0.f;
    #pragma unroll
    for (int r = 0; r < 4; ++r)
      tv += (acc[nf][r] - mu[r]) * rs[r];
    tv = tv*g + 4.f*bv;
    if (lk >= 2) tv = 0.f;              // rows 8..15 are garbage (M=8)
    tv += __shfl_xor(tv, 16); tv += __shfl_xor(tv, 32);
    if (lk == 0)
      atomicAdd(&ctxsum[b0*768 + n], tv);
  }
}

// =====================================================================
// D3: k_hpre — hpre += v @ W1 (+b1). Grid 96 = 24n(32col) x 4k(192c).
// 16 partial accumulators (round-8 ILP win).
// =====================================================================
__global__ void k_hpre(const float* __restrict__ qt, const float* __restrict__ ctxsum,
                       const float* __restrict__ W1, const float* __restrict__ b1,
                       float* __restrict__ hpre){
  __shared__ float vsh[Bn][192];
  int nc = blockIdx.x % 24, kc = blockIdx.x / 24;
  int n0 = nc*32, c0 = kc*192;
  int t = threadIdx.x;
  for (int i = t; i < Bn*192; i += 256){
    int b = i / 192, cl = i - b*192;
    int c = c0 + cl;
    const float* q = qt + (size_t)b*6*768;
    float pm = q[768+c] + q[2*768+c] + q[3*768+c] + q[4*768+c] + q[5*768+c];
    vsh[b][cl] = q[c] + 0.2f*pm + ctxsum[b*768 + c]*(1.f/680.f);
  }
  __syncthreads();
  int ow = t & 31, bi = t >> 5;
  int o = n0 + ow;
  const float* w = W1 + (size_t)c0*768 + o;
  float pacc[16];
  #pragma unroll
  for (int i = 0; i < 16; ++i) pacc[i] = 0.f;
  for (int cl = 0; cl < 192; cl += 16){
    #pragma unroll
    for (int i = 0; i < 16; ++i)
      pacc[i] = fmaf(vsh[bi][cl + i], w[(size_t)(cl + i)*768], pacc[i]);
  }
  float acc = ((pacc[0]+pacc[1])+(pacc[2]+pacc[3])) + ((pacc[4]+pacc[5])+(pacc[6]+pacc[7]))
            + ((pacc[8]+pacc[9])+(pacc[10]+pacc[11])) + ((pacc[12]+pacc[13])+(pacc[14]+pacc[15]));
  if (kc == 0) acc += b1[o];
  atomicAdd(&hpre[bi*768 + o], acc);
}

// =====================================================================
// D4: k_out — out += relu(hpre) @ W2 (+b2). Grid 52 = 13n(32) x 4k(192).
// =====================================================================
__global__ void k_out(const float* __restrict__ hpre, const float* __restrict__ W2,
                      const float* __restrict__ b2, float* __restrict__ out){
  __shared__ float hsh[Bn][192];
  int nc = blockIdx.x % 13, kc = blockIdx.x / 13;
  int n0 = nc*32, c0 = kc*192;
  int t = threadIdx.x;
  for (int i = t; i < Bn*192; i += 256){
    int b = i / 192, cl = i - b*192;
    hsh[b][cl] = fmaxf(hpre[b*768 + c0 + cl], 0.f);
  }
  __syncthreads();
  int ow = t & 31, bi = t >> 5;
  int o = n0 + ow;
  if (o >= NCn) return;
  const float* w = W2 + (size_t)c0*NCn + o;
  float pacc[16];
  #pragma unroll
  for (int i = 0; i < 16; ++i) pacc[i] = 0.f;
  for (int cl = 0; cl < 192; cl += 16){
    #pragma unroll
    for (int i = 0; i < 16; ++i)
      pacc[i] = fmaf(hsh[bi][cl + i], w[(size_t)(cl + i)*NCn], pacc[i]);
  }
  float acc = ((pacc[0]+pacc[1])+(pacc[2]+pacc[3])) + ((pacc[4]+pacc[5])+(pacc[6]+pacc[7]))
            + ((pacc[8]+pacc[9])+(pacc[10]+pacc[11])) + ((pacc[12]+pacc[13])+(pacc[14]+pacc[15]));
  if (kc == 0) acc += b2[o];
  atomicAdd(&out[bi*NCn + o], acc);
}

extern "C" void kernel_launch(void* const* d_in, const int* in_sizes, int n_in,
                              void* d_out, int out_size, void* d_ws, size_t ws_size,
                              hipStream_t stream){
  const float* pl = (const float*)d_in[0];
  const float* hs = (const float*)d_in[2];
  const float* feat[4]; const float* pos[4]; const void* mask[4];
  const float* cw[4]; const float* cb[4]; const float* lg[4]; const float* lb[4];
  for (int s = 0; s < 4; ++s){
    int base = 3 + 7*s;
    feat[s] = (const float*)d_in[base];
    pos[s]  = (const float*)d_in[base+1];
    mask[s] = d_in[base+2];
    cw[s]   = (const float*)d_in[base+3];
    cb[s]   = (const float*)d_in[base+4];
    lg[s]   = (const float*)d_in[base+5];
    lb[s]   = (const float*)d_in[base+6];
  }
  const float* lq  = (const float*)d_in[31];
  const float* Wq  = (const float*)d_in[32];
  const float* bq  = (const float*)d_in[33];
  const float* qng = (const float*)d_in[34];
  const float* qnb = (const float*)d_in[35];
  const float* W1  = (const float*)d_in[36];
  const float* b1  = (const float*)d_in[37];
  const float* W2  = (const float*)d_in[38];
  const float* b2  = (const float*)d_in[39];
  float* out = (float*)d_out;

  // ---- workspace layout (~1.7 MB)
  short* Wswz   = (short*)d_ws;                        // [4][8][4][768][8] bf16 = 1.5 MB
  float* pooled = (float*)(Wswz + (size_t)4*8*4*768*8);// 40*256
  float* qt     = pooled + 40*RSn;                     // 8*6*768
  float* ctxsum = qt + Bn*6*QSn;                       // 8*768 (zeroed by k_front)
  float* hpre   = ctxsum + Bn*QSn;                     // 8*768 (zeroed by k_front)
  int*   det    = (int*)(hpre + Bn*QSn);               // 2 ints
  int*   flags  = det + 4;                             // 40 ints

  k_front<<<825, 256, 0, stream>>>(cw[0], cw[1], cw[2], cw[3], Wswz,
                                   (const int*)mask[0], det, pl, hs, pooled, flags,
                                   ctxsum, out);
  k_pgemm<<<1408, 128, 0, stream>>>(feat[0], pos[0], mask[0],
                                    feat[1], pos[1], mask[1],
                                    feat[2], pos[2], mask[2],
                                    feat[3], pos[3], mask[3],
                                    det, Wswz,
                                    cb[0], cb[1], cb[2], cb[3],
                                    lg[0], lb[0], lg[1], lb[1],
                                    lg[2], lb[2], lg[3], lb[3], ctxsum,
                                    lq, Wq, bq, qng, qnb, pooled, flags, qt);
  k_hpre<<<96, 256, 0, stream>>>(qt, ctxsum, W1, b1, hpre);
  k_out<<<52, 256, 0, stream>>>(hpre, W2, b2, out);
}